// Round 1
// baseline (10379.717 us; speedup 1.0000x reference)
//
#include <hip/hip_runtime.h>
#include <math.h>

// RNN: L=512, B=128, D=512, H=1024, fp32 in/out.
//   xproj = x @ Wx^T + bx   (65536x1024x512 GEMM) -> written into d_out
//   h_t = tanh(xp_t + h_{t-1} @ Wh^T), in-place over d_out slices.
// Precision: split-bf16 (hi+lo) operands, 3 MFMAs per product => ~fp32 accuracy.

#define L_SEQ 512
#define B_SZ  128
#define D_SZ  512
#define H_SZ  1024
#define BH    (B_SZ * H_SZ)   // 131072

typedef __bf16 bf16x8 __attribute__((ext_vector_type(8)));
typedef float  f32x4  __attribute__((ext_vector_type(4)));

union V8 { bf16x8 b; unsigned short u[8]; };

__device__ __forceinline__ unsigned short f2bf(float f) {
  unsigned int u = __float_as_uint(f);
  u += 0x7FFFu + ((u >> 16) & 1u);   // round-to-nearest-even
  return (unsigned short)(u >> 16);
}
__device__ __forceinline__ float bf2f(unsigned short s) {
  return __uint_as_float(((unsigned int)s) << 16);
}

// ---- d_ws layout (elements of ushort/bf16) ----
// whh : [1024][1024]            @ 0
// whl : [1024][1024]            @ 1048576
// wxh : [1024][512]             @ 2097152
// wxl : [1024][512]             @ 2621440
// hb  : [2 parity][2 hi/lo][BH] @ 3145728   (total 3670016 elems = 7 MB)
#define WS_WHH 0
#define WS_WHL 1048576
#define WS_WXH 2097152
#define WS_WXL 2621440
#define WS_HB  3145728

// Split fp32 weights into bf16 hi + bf16 lo(residual).
__global__ void split_kernel(const float* __restrict__ Wh,
                             const float* __restrict__ Wx,
                             unsigned short* __restrict__ ws) {
  const int total = 1048576 + 524288;
  for (int i = blockIdx.x * blockDim.x + threadIdx.x; i < total;
       i += gridDim.x * blockDim.x) {
    const float* src; unsigned short *dh, *dl; int j;
    if (i < 1048576) { src = Wh; dh = ws + WS_WHH; dl = ws + WS_WHL; j = i; }
    else             { src = Wx; dh = ws + WS_WXH; dl = ws + WS_WXL; j = i - 1048576; }
    float v = src[j];
    unsigned short h = f2bf(v);
    dh[j] = h;
    dl[j] = f2bf(v - bf2f(h));
  }
}

// xproj: out[m][n] = sum_d x[m][d]*Wx[n][d] + bx[n],  m in [0,65536), n in [0,1024)
// Tile: BM=128, BN=64. 4 waves as 2(M)x2(N); wave tile 64x32 (msub=4, nsub=2).
// x split to bf16 hi/lo on the fly; Wx pre-split. 3 MFMAs per (i,j) per K-chunk.
__global__ __launch_bounds__(256) void xproj_kernel(
    const float* __restrict__ x,             // [65536][512]
    const unsigned short* __restrict__ wxh,  // [1024][512]
    const unsigned short* __restrict__ wxl,
    const float* __restrict__ bx,            // [1024]
    float* __restrict__ out)                 // [65536][1024]
{
  const int bid = blockIdx.x;
  const int bn = bid & 15;       // 16 N-blocks (fastest: neighbors share x rows)
  const int bm = bid >> 4;       // 512 M-blocks
  const int tid = threadIdx.x;
  const int w = tid >> 6, l = tid & 63;
  const int wm = w & 1, wn = w >> 1;
  const int lr = l & 15, lk = (l >> 4) * 8;
  const int mbase = bm * 128 + wm * 64;
  const int nbase = bn * 64 + wn * 32;

  f32x4 acc[4][2] = {};

  for (int k0 = 0; k0 < 512; k0 += 32) {
    bf16x8 ah[4], al[4], bh[2], bl[2];
#pragma unroll
    for (int i = 0; i < 4; ++i) {
      const float* ap = x + (size_t)(mbase + i * 16 + lr) * 512 + k0 + lk;
      float4 v0 = *reinterpret_cast<const float4*>(ap);
      float4 v1 = *reinterpret_cast<const float4*>(ap + 4);
      float vv[8] = {v0.x, v0.y, v0.z, v0.w, v1.x, v1.y, v1.z, v1.w};
      V8 hh, ll;
#pragma unroll
      for (int e = 0; e < 8; ++e) {
        unsigned short hb = f2bf(vv[e]);
        hh.u[e] = hb;
        ll.u[e] = f2bf(vv[e] - bf2f(hb));
      }
      ah[i] = hh.b; al[i] = ll.b;
    }
#pragma unroll
    for (int j = 0; j < 2; ++j) {
      size_t boff = (size_t)(nbase + j * 16 + lr) * 512 + k0 + lk;
      bh[j] = *reinterpret_cast<const bf16x8*>(wxh + boff);
      bl[j] = *reinterpret_cast<const bf16x8*>(wxl + boff);
    }
#pragma unroll
    for (int i = 0; i < 4; ++i)
#pragma unroll
      for (int j = 0; j < 2; ++j) {
        acc[i][j] = __builtin_amdgcn_mfma_f32_16x16x32_bf16(ah[i], bh[j], acc[i][j], 0, 0, 0);
        acc[i][j] = __builtin_amdgcn_mfma_f32_16x16x32_bf16(ah[i], bl[j], acc[i][j], 0, 0, 0);
        acc[i][j] = __builtin_amdgcn_mfma_f32_16x16x32_bf16(al[i], bh[j], acc[i][j], 0, 0, 0);
      }
  }

  // Epilogue. C/D layout (verified m89/m91): col = lane&15, row = (lane>>4)*4 + reg.
#pragma unroll
  for (int j = 0; j < 2; ++j) {
    int n = nbase + j * 16 + lr;
    float bxv = bx[n];
#pragma unroll
    for (int i = 0; i < 4; ++i)
#pragma unroll
      for (int r = 0; r < 4; ++r) {
        int m = mbase + i * 16 + (l >> 4) * 4 + r;
        out[(size_t)m * 1024 + n] = acc[i][j][r] + bxv;
      }
  }
}

// t = 0: h_0 = tanh(xp_0); also emit bf16 hi/lo into hb parity 0.
__global__ void step0_kernel(float* __restrict__ xp,
                             unsigned short* __restrict__ hch,
                             unsigned short* __restrict__ hcl) {
  int i = blockIdx.x * 256 + threadIdx.x;   // grid 512*256 == BH exactly
  float h = tanhf(xp[i]);
  xp[i] = h;
  unsigned short hb = f2bf(h);
  hch[i] = hb;
  hcl[i] = f2bf(h - bf2f(hb));
}

// One recurrence step: z[128][1024] = h_prev @ Wh^T (split 3-MFMA) ; h = tanh(z + xp).
// Grid 128 WGs: BM=16 (bm in 0..7), BN=64 (bn in 0..15); 4 waves, wave tile 16x16.
// No LDS: fragments read directly from L2 (Wh hot), even/odd-K dual accumulators for ILP.
__global__ __launch_bounds__(256) void step_kernel(
    const unsigned short* __restrict__ whh,  // [1024][1024]
    const unsigned short* __restrict__ whl,
    const unsigned short* __restrict__ hph,  // h_{t-1} hi [128][1024]
    const unsigned short* __restrict__ hpl,  // h_{t-1} lo
    float* __restrict__ xp,                  // d_out + t*BH (in: xproj, out: h_t)
    unsigned short* __restrict__ hch,        // h_t hi out
    unsigned short* __restrict__ hcl)        // h_t lo out
{
  const int bid = blockIdx.x;
  const int bm = bid & 7, bn = bid >> 3;
  const int tid = threadIdx.x;
  const int w = tid >> 6, l = tid & 63;
  const int lr = l & 15, lk = (l >> 4) * 8;
  const int arow = bm * 16 + lr;             // A row (batch index within block)
  const int nrow = bn * 64 + w * 16 + lr;    // B row (output-column index)

  const unsigned short* ap_h = hph + (size_t)arow * 1024 + lk;
  const unsigned short* ap_l = hpl + (size_t)arow * 1024 + lk;
  const unsigned short* bp_h = whh + (size_t)nrow * 1024 + lk;
  const unsigned short* bp_l = whl + (size_t)nrow * 1024 + lk;

  f32x4 acc0 = {0.f, 0.f, 0.f, 0.f};
  f32x4 acc1 = {0.f, 0.f, 0.f, 0.f};

#pragma unroll 4
  for (int k0 = 0; k0 < 1024; k0 += 64) {
    bf16x8 a0h = *reinterpret_cast<const bf16x8*>(ap_h + k0);
    bf16x8 a0l = *reinterpret_cast<const bf16x8*>(ap_l + k0);
    bf16x8 b0h = *reinterpret_cast<const bf16x8*>(bp_h + k0);
    bf16x8 b0l = *reinterpret_cast<const bf16x8*>(bp_l + k0);
    bf16x8 a1h = *reinterpret_cast<const bf16x8*>(ap_h + k0 + 32);
    bf16x8 a1l = *reinterpret_cast<const bf16x8*>(ap_l + k0 + 32);
    bf16x8 b1h = *reinterpret_cast<const bf16x8*>(bp_h + k0 + 32);
    bf16x8 b1l = *reinterpret_cast<const bf16x8*>(bp_l + k0 + 32);
    acc0 = __builtin_amdgcn_mfma_f32_16x16x32_bf16(a0h, b0h, acc0, 0, 0, 0);
    acc1 = __builtin_amdgcn_mfma_f32_16x16x32_bf16(a1h, b1h, acc1, 0, 0, 0);
    acc0 = __builtin_amdgcn_mfma_f32_16x16x32_bf16(a0h, b0l, acc0, 0, 0, 0);
    acc1 = __builtin_amdgcn_mfma_f32_16x16x32_bf16(a1h, b1l, acc1, 0, 0, 0);
    acc0 = __builtin_amdgcn_mfma_f32_16x16x32_bf16(a0l, b0h, acc0, 0, 0, 0);
    acc1 = __builtin_amdgcn_mfma_f32_16x16x32_bf16(a1l, b1h, acc1, 0, 0, 0);
  }
  f32x4 acc = acc0 + acc1;

  // Epilogue: z += xp, h = tanh, write fp32 h (in place) + bf16 hi/lo state.
  const int n = bn * 64 + w * 16 + lr;       // col = lane&15
#pragma unroll
  for (int r = 0; r < 4; ++r) {
    int m = bm * 16 + (l >> 4) * 4 + r;      // row = (lane>>4)*4 + reg
    size_t idx = (size_t)m * 1024 + n;
    float z = acc[r] + xp[idx];
    float h = tanhf(z);
    xp[idx] = h;
    unsigned short hb = f2bf(h);
    hch[idx] = hb;
    hcl[idx] = f2bf(h - bf2f(hb));
  }
}

extern "C" void kernel_launch(void* const* d_in, const int* in_sizes, int n_in,
                              void* d_out, int out_size, void* d_ws, size_t ws_size,
                              hipStream_t stream) {
  const float* x  = (const float*)d_in[0];   // [512][128][512]
  const float* Wx = (const float*)d_in[1];   // [1024][512]
  const float* bx = (const float*)d_in[2];   // [1024]
  const float* Wh = (const float*)d_in[3];   // [1024][1024]
  float* out = (float*)d_out;                // [512][128][1024]
  unsigned short* ws = (unsigned short*)d_ws;

  unsigned short* whh = ws + WS_WHH;
  unsigned short* whl = ws + WS_WHL;
  unsigned short* wxh = ws + WS_WXH;
  unsigned short* wxl = ws + WS_WXL;
  unsigned short* hb  = ws + WS_HB;          // [2][2][BH]

  split_kernel<<<dim3(2048), dim3(256), 0, stream>>>(Wh, Wx, ws);
  xproj_kernel<<<dim3(8192), dim3(256), 0, stream>>>(x, wxh, wxl, bx, out);
  step0_kernel<<<dim3(512), dim3(256), 0, stream>>>(out, hb, hb + BH);

  for (int t = 1; t < L_SEQ; ++t) {
    unsigned short* hp = hb + (size_t)((t - 1) & 1) * (2 * BH);
    unsigned short* hc = hb + (size_t)(t & 1) * (2 * BH);
    step_kernel<<<dim3(128), dim3(256), 0, stream>>>(
        whh, whl, hp, hp + BH, out + (size_t)t * BH, hc, hc + BH);
  }
}

// Round 2
// 4788.374 us; speedup vs baseline: 2.1677x; 2.1677x over previous
//
#include <hip/hip_runtime.h>
#include <math.h>

// RNN: L=512, B=128, D=512, H=1024, fp32 in/out.
//   xproj = x @ Wx^T + bx   (65536x1024x512 GEMM) -> written into d_out
//   h_t = tanh(xp_t + h_{t-1} @ Wh^T), in-place over d_out slices.
// Precision: split-bf16 (hi+lo) operands, 3 MFMAs per product => ~fp32 accuracy.
// Round 2: step kernel restructured — 256 WGs x 8 waves, K-split-8 per wave,
// LDS reduction; XCD-aware tile map so each XCD's L2 keeps a fixed 2MB Wh slice.

#define L_SEQ 512
#define B_SZ  128
#define D_SZ  512
#define H_SZ  1024
#define BH    (B_SZ * H_SZ)   // 131072

typedef __bf16 bf16x8 __attribute__((ext_vector_type(8)));
typedef float  f32x4  __attribute__((ext_vector_type(4)));

union V8 { bf16x8 b; unsigned short u[8]; };

__device__ __forceinline__ unsigned short f2bf(float f) {
  unsigned int u = __float_as_uint(f);
  u += 0x7FFFu + ((u >> 16) & 1u);   // round-to-nearest-even
  return (unsigned short)(u >> 16);
}
__device__ __forceinline__ float bf2f(unsigned short s) {
  return __uint_as_float(((unsigned int)s) << 16);
}

// ---- d_ws layout (elements of ushort/bf16) ----
#define WS_WHH 0
#define WS_WHL 1048576
#define WS_WXH 2097152
#define WS_WXL 2621440
#define WS_HB  3145728   // [2 parity][2 hi/lo][BH]

// Split fp32 weights into bf16 hi + bf16 lo(residual).
__global__ void split_kernel(const float* __restrict__ Wh,
                             const float* __restrict__ Wx,
                             unsigned short* __restrict__ ws) {
  const int total = 1048576 + 524288;
  for (int i = blockIdx.x * blockDim.x + threadIdx.x; i < total;
       i += gridDim.x * blockDim.x) {
    const float* src; unsigned short *dh, *dl; int j;
    if (i < 1048576) { src = Wh; dh = ws + WS_WHH; dl = ws + WS_WHL; j = i; }
    else             { src = Wx; dh = ws + WS_WXH; dl = ws + WS_WXL; j = i - 1048576; }
    float v = src[j];
    unsigned short h = f2bf(v);
    dh[j] = h;
    dl[j] = f2bf(v - bf2f(h));
  }
}

// xproj: out[m][n] = sum_d x[m][d]*Wx[n][d] + bx[n]  (unchanged from round 1)
__global__ __launch_bounds__(256) void xproj_kernel(
    const float* __restrict__ x,             // [65536][512]
    const unsigned short* __restrict__ wxh,  // [1024][512]
    const unsigned short* __restrict__ wxl,
    const float* __restrict__ bx,            // [1024]
    float* __restrict__ out)                 // [65536][1024]
{
  const int bid = blockIdx.x;
  const int bn = bid & 15;
  const int bm = bid >> 4;
  const int tid = threadIdx.x;
  const int w = tid >> 6, l = tid & 63;
  const int wm = w & 1, wn = w >> 1;
  const int lr = l & 15, lk = (l >> 4) * 8;
  const int mbase = bm * 128 + wm * 64;
  const int nbase = bn * 64 + wn * 32;

  f32x4 acc[4][2] = {};

  for (int k0 = 0; k0 < 512; k0 += 32) {
    bf16x8 ah[4], al[4], bh[2], bl[2];
#pragma unroll
    for (int i = 0; i < 4; ++i) {
      const float* ap = x + (size_t)(mbase + i * 16 + lr) * 512 + k0 + lk;
      float4 v0 = *reinterpret_cast<const float4*>(ap);
      float4 v1 = *reinterpret_cast<const float4*>(ap + 4);
      float vv[8] = {v0.x, v0.y, v0.z, v0.w, v1.x, v1.y, v1.z, v1.w};
      V8 hh, ll;
#pragma unroll
      for (int e = 0; e < 8; ++e) {
        unsigned short hb = f2bf(vv[e]);
        hh.u[e] = hb;
        ll.u[e] = f2bf(vv[e] - bf2f(hb));
      }
      ah[i] = hh.b; al[i] = ll.b;
    }
#pragma unroll
    for (int j = 0; j < 2; ++j) {
      size_t boff = (size_t)(nbase + j * 16 + lr) * 512 + k0 + lk;
      bh[j] = *reinterpret_cast<const bf16x8*>(wxh + boff);
      bl[j] = *reinterpret_cast<const bf16x8*>(wxl + boff);
    }
#pragma unroll
    for (int i = 0; i < 4; ++i)
#pragma unroll
      for (int j = 0; j < 2; ++j) {
        acc[i][j] = __builtin_amdgcn_mfma_f32_16x16x32_bf16(ah[i], bh[j], acc[i][j], 0, 0, 0);
        acc[i][j] = __builtin_amdgcn_mfma_f32_16x16x32_bf16(ah[i], bl[j], acc[i][j], 0, 0, 0);
        acc[i][j] = __builtin_amdgcn_mfma_f32_16x16x32_bf16(al[i], bh[j], acc[i][j], 0, 0, 0);
      }
  }

#pragma unroll
  for (int j = 0; j < 2; ++j) {
    int n = nbase + j * 16 + lr;
    float bxv = bx[n];
#pragma unroll
    for (int i = 0; i < 4; ++i)
#pragma unroll
      for (int r = 0; r < 4; ++r) {
        int m = mbase + i * 16 + (l >> 4) * 4 + r;
        out[(size_t)m * 1024 + n] = acc[i][j][r] + bxv;
      }
  }
}

// t = 0: h_0 = tanh(xp_0); emit bf16 hi/lo into hb parity 0.
__global__ void step0_kernel(float* __restrict__ xp,
                             unsigned short* __restrict__ hch,
                             unsigned short* __restrict__ hcl) {
  int i = blockIdx.x * 256 + threadIdx.x;   // grid 512*256 == BH exactly
  float h = tanhf(xp[i]);
  xp[i] = h;
  unsigned short hb = f2bf(h);
  hch[i] = hb;
  hcl[i] = f2bf(h - bf2f(hb));
}

// One recurrence step (v2): z[128][1024] = h_prev @ Wh^T (split 3-MFMA); h = tanh(z+xp).
// 256 WGs x 512 threads (8 waves). Tile = 32(M) x 16(N); wave q owns K-slice of 128.
// 2048 waves => 2 waves/SIMD on all 256 CUs. LDS reduction of 8 partials.
// XCD map: x=wg&7 -> mb=x&3, nb=(x>>2)*32+(wg>>3): each XCD's L2 holds a fixed
// 2MB Wh slice (resident across all 512 steps) + that step's 32 h_prev rows.
__global__ __launch_bounds__(512) void step_kernel(
    const unsigned short* __restrict__ whh,  // [1024][1024]
    const unsigned short* __restrict__ whl,
    const unsigned short* __restrict__ hph,  // h_{t-1} hi [128][1024]
    const unsigned short* __restrict__ hpl,  // h_{t-1} lo
    float* __restrict__ xp,                  // d_out + t*BH (in: xproj, out: h_t)
    unsigned short* __restrict__ hch,        // h_t hi out
    unsigned short* __restrict__ hcl)        // h_t lo out
{
  __shared__ float lds[8 * 32 * 17];         // 17408 B, stride-17 pad
  const int wg = blockIdx.x;                 // 0..255
  const int xc = wg & 7, yy = wg >> 3;
  const int mb = xc & 3;                     // 4 M-blocks of 32 rows
  const int nb = ((xc >> 2) << 5) + yy;      // 64 N-blocks of 16 cols
  const int tid = threadIdx.x;
  const int q = tid >> 6;                    // k-slice 0..7 (K=128 each)
  const int l = tid & 63;
  const int lr = l & 15, lk = (l >> 4) * 8;
  const int kbase = q * 128 + lk;

  const unsigned short* a0h = hph + (size_t)(mb * 32 + lr) * 1024 + kbase;
  const unsigned short* a0l = hpl + (size_t)(mb * 32 + lr) * 1024 + kbase;
  const unsigned short* a1h = a0h + 16 * 1024;
  const unsigned short* a1l = a0l + 16 * 1024;
  const unsigned short* bph = whh + (size_t)(nb * 16 + lr) * 1024 + kbase;
  const unsigned short* bpl = whl + (size_t)(nb * 16 + lr) * 1024 + kbase;

  f32x4 acc0 = {0.f, 0.f, 0.f, 0.f};
  f32x4 acc1 = {0.f, 0.f, 0.f, 0.f};

#pragma unroll
  for (int kb = 0; kb < 4; ++kb) {
    const int ko = kb * 32;
    bf16x8 vA0h = *reinterpret_cast<const bf16x8*>(a0h + ko);
    bf16x8 vA0l = *reinterpret_cast<const bf16x8*>(a0l + ko);
    bf16x8 vA1h = *reinterpret_cast<const bf16x8*>(a1h + ko);
    bf16x8 vA1l = *reinterpret_cast<const bf16x8*>(a1l + ko);
    bf16x8 vBh  = *reinterpret_cast<const bf16x8*>(bph + ko);
    bf16x8 vBl  = *reinterpret_cast<const bf16x8*>(bpl + ko);
    acc0 = __builtin_amdgcn_mfma_f32_16x16x32_bf16(vA0h, vBh, acc0, 0, 0, 0);
    acc1 = __builtin_amdgcn_mfma_f32_16x16x32_bf16(vA1h, vBh, acc1, 0, 0, 0);
    acc0 = __builtin_amdgcn_mfma_f32_16x16x32_bf16(vA0h, vBl, acc0, 0, 0, 0);
    acc1 = __builtin_amdgcn_mfma_f32_16x16x32_bf16(vA1h, vBl, acc1, 0, 0, 0);
    acc0 = __builtin_amdgcn_mfma_f32_16x16x32_bf16(vA0l, vBh, acc0, 0, 0, 0);
    acc1 = __builtin_amdgcn_mfma_f32_16x16x32_bf16(vA1l, vBh, acc1, 0, 0, 0);
  }

  // Partials -> LDS. C/D layout: col = lane&15, row = (lane>>4)*4 + r.
  const int row0 = (l >> 4) * 4;
#pragma unroll
  for (int r = 0; r < 4; ++r) {
    lds[q * 544 + (row0 + r) * 17 + lr]        = acc0[r];
    lds[q * 544 + (16 + row0 + r) * 17 + lr]   = acc1[r];
  }
  __syncthreads();

  // Epilogue: one output element per thread (32x16 = 512 = blockDim).
  const int m = tid >> 4, n = tid & 15;
  float s = 0.f;
#pragma unroll
  for (int qq = 0; qq < 8; ++qq) s += lds[qq * 544 + m * 17 + n];
  const size_t idx = (size_t)(mb * 32 + m) * 1024 + nb * 16 + n;
  float z = s + xp[idx];
  float h = tanhf(z);
  xp[idx] = h;
  unsigned short hbv = f2bf(h);
  hch[idx] = hbv;
  hcl[idx] = f2bf(h - bf2f(hbv));
}

extern "C" void kernel_launch(void* const* d_in, const int* in_sizes, int n_in,
                              void* d_out, int out_size, void* d_ws, size_t ws_size,
                              hipStream_t stream) {
  const float* x  = (const float*)d_in[0];   // [512][128][512]
  const float* Wx = (const float*)d_in[1];   // [1024][512]
  const float* bx = (const float*)d_in[2];   // [1024]
  const float* Wh = (const float*)d_in[3];   // [1024][1024]
  float* out = (float*)d_out;                // [512][128][1024]
  unsigned short* ws = (unsigned short*)d_ws;

  unsigned short* whh = ws + WS_WHH;
  unsigned short* whl = ws + WS_WHL;
  unsigned short* wxh = ws + WS_WXH;
  unsigned short* wxl = ws + WS_WXL;
  unsigned short* hb  = ws + WS_HB;          // [2][2][BH]

  split_kernel<<<dim3(2048), dim3(256), 0, stream>>>(Wh, Wx, ws);
  xproj_kernel<<<dim3(8192), dim3(256), 0, stream>>>(x, wxh, wxl, bx, out);
  step0_kernel<<<dim3(512), dim3(256), 0, stream>>>(out, hb, hb + BH);

  for (int t = 1; t < L_SEQ; ++t) {
    unsigned short* hp = hb + (size_t)((t - 1) & 1) * (2 * BH);
    unsigned short* hc = hb + (size_t)(t & 1) * (2 * BH);
    step_kernel<<<dim3(256), dim3(512), 0, stream>>>(
        whh, whl, hp, hp + BH, out + (size_t)t * BH, hc, hc + BH);
  }
}